// Round 1
// baseline (753.534 us; speedup 1.0000x reference)
//
#include <hip/hip_runtime.h>
#include <stdint.h>

#define NGRAPH 2048
#define MNODES 128
#define HID 256
#define OUTC 12
#define NEDGE 2097152

typedef __attribute__((ext_vector_type(8))) short short8;
typedef __attribute__((ext_vector_type(4))) float v4f;

#define SA_STRIDE 136   // 128 + 8 pad (keeps 16B alignment, bank-uniform)
#define SWT_STRIDE 136
#define LDS_A_ELEMS (MNODES * SA_STRIDE)
#define LDS_WT_ELEMS (HID * SWT_STRIDE)
#define LDS_BYTES (LDS_A_ELEMS * 2 + LDS_WT_ELEMS * 2 + 6 * HID * 4)

__device__ __forceinline__ unsigned short f2bf(float f) {
    unsigned int u = __builtin_bit_cast(unsigned int, f);
    u += 0x7fffu + ((u >> 16) & 1u);   // round-to-nearest-even
    return (unsigned short)(u >> 16);
}

// Kernel 1: scatter edges into per-graph 128x128 adjacency bitmask.
// OR is idempotent -> matches assignment (.set(1.0)) semantics exactly.
__global__ void build_adj(const int* __restrict__ ei, unsigned int* __restrict__ bits) {
    int e = blockIdx.x * blockDim.x + threadIdx.x;
    if (e >= NEDGE) return;
    int s = ei[e];
    int d = ei[NEDGE + e];
    int g = s >> 7;            // uniform graphs: node i -> graph i/128
    int li = s & 127;
    int lj = d & 127;
    unsigned int* base = bits + (size_t)g * (MNODES * 4);
    atomicOr(&base[li * 4 + (lj >> 5)], 1u << (lj & 31));
    atomicOr(&base[lj * 4 + (li >> 5)], 1u << (li & 31));
}

// Kernel 2: one workgroup per graph. 8 waves, each owns a 64x64 output region
// (4x4 tiles of 16x16). walk stored TRANSPOSED in LDS so B-fragments are
// contiguous 16B reads. X kept in fp32 registers in MFMA C-layout.
__launch_bounds__(512, 2)
__global__ void walk_kernel(const float* __restrict__ x,
                            const float* __restrict__ W,
                            const float* __restrict__ bvec,
                            const unsigned int* __restrict__ bits,
                            float* __restrict__ out) {
    extern __shared__ char smem[];
    unsigned short* sA = (unsigned short*)smem;                       // [128][136] bf16
    unsigned short* sWT = (unsigned short*)(smem + LDS_A_ELEMS * 2);  // [256][136] bf16 (walk^T)
    float* sVs = (float*)(smem + LDS_A_ELEMS * 2 + LDS_WT_ELEMS * 2); // [6][256] fp32

    const int g = blockIdx.x;
    const int tid = threadIdx.x;
    const int wave = tid >> 6;
    const int lane = tid & 63;
    const int lrow = lane & 15;
    const int quad = lane >> 4;
    const int r0 = (wave & 1) * 64;   // output row base (nodes)
    const int c0 = (wave >> 1) * 64;  // output col base (hidden)

    // ---- phase 0: zero vs accumulators, expand adjacency bitmask -> bf16 LDS
    for (int i = tid; i < 6 * HID; i += 512) sVs[i] = 0.0f;
    {
        unsigned int wbits = bits[g * (MNODES * 4) + tid]; // 512 words exactly
        int r = tid >> 2, wq = tid & 3;
        unsigned int* dst = (unsigned int*)(sA + r * SA_STRIDE + wq * 32);
#pragma unroll
        for (int i = 0; i < 16; i++) {
            unsigned int v = ((wbits >> (2 * i)) & 1u) ? 0x3F80u : 0u;
            v |= (((wbits >> (2 * i + 1)) & 1u) ? 0x3F80u : 0u) << 16;
            dst[i] = v;
        }
    }

    // ---- phase 1: load X fragments (fp32, C-layout), init walk1 = X, v1 sums
    float xf[4][4][4];
    const float* xg = x + (size_t)g * MNODES * HID;
#pragma unroll
    for (int rt = 0; rt < 4; rt++) {
#pragma unroll
        for (int ct = 0; ct < 4; ct++) {
            int col = c0 + ct * 16 + lrow;
#pragma unroll
            for (int reg = 0; reg < 4; reg++) {
                int row = r0 + rt * 16 + quad * 4 + reg;
                xf[rt][ct][reg] = xg[row * HID + col];
            }
        }
    }
#pragma unroll
    for (int ct = 0; ct < 4; ct++) {
        int col = c0 + ct * 16 + lrow;
        float cs = 0.0f;
#pragma unroll
        for (int rt = 0; rt < 4; rt++) {
            int nbase = r0 + rt * 16 + quad * 4;
            uint2 u;
            u.x = (unsigned)f2bf(xf[rt][ct][0]) | ((unsigned)f2bf(xf[rt][ct][1]) << 16);
            u.y = (unsigned)f2bf(xf[rt][ct][2]) | ((unsigned)f2bf(xf[rt][ct][3]) << 16);
            *(uint2*)(sWT + col * SWT_STRIDE + nbase) = u;
            cs += xf[rt][ct][0] + xf[rt][ct][1] + xf[rt][ct][2] + xf[rt][ct][3];
        }
        cs += __shfl_xor(cs, 16);
        cs += __shfl_xor(cs, 32);
        if (quad == 0) atomicAdd(&sVs[col], cs);
    }

    // ---- 5 walk iterations: Y = A @ walk (MFMA), walk = Y .* X, vs[k] = colsum
    for (int it = 1; it <= 5; it++) {
        __syncthreads();  // sWT (and sA/sVs on first pass) ready
        v4f acc[4][4];
#pragma unroll
        for (int rt = 0; rt < 4; rt++)
#pragma unroll
            for (int ct = 0; ct < 4; ct++) acc[rt][ct] = (v4f)(0.0f);
#pragma unroll
        for (int ks = 0; ks < 4; ks++) {
            int k0 = ks * 32 + quad * 8;
            short8 a[4];
#pragma unroll
            for (int rt = 0; rt < 4; rt++)
                a[rt] = *(const short8*)(sA + (r0 + rt * 16 + lrow) * SA_STRIDE + k0);
#pragma unroll
            for (int ct = 0; ct < 4; ct++) {
                short8 bf = *(const short8*)(sWT + (c0 + ct * 16 + lrow) * SWT_STRIDE + k0);
#pragma unroll
                for (int rt = 0; rt < 4; rt++)
                    acc[rt][ct] = __builtin_amdgcn_mfma_f32_16x16x32_bf16(a[rt], bf, acc[rt][ct], 0, 0, 0);
            }
        }
        __syncthreads();  // all reads of sWT done before overwrite
#pragma unroll
        for (int ct = 0; ct < 4; ct++) {
            int col = c0 + ct * 16 + lrow;
            float cs = 0.0f;
#pragma unroll
            for (int rt = 0; rt < 4; rt++) {
                float nw0 = acc[rt][ct][0] * xf[rt][ct][0];
                float nw1 = acc[rt][ct][1] * xf[rt][ct][1];
                float nw2 = acc[rt][ct][2] * xf[rt][ct][2];
                float nw3 = acc[rt][ct][3] * xf[rt][ct][3];
                int nbase = r0 + rt * 16 + quad * 4;
                uint2 u;
                u.x = (unsigned)f2bf(nw0) | ((unsigned)f2bf(nw1) << 16);
                u.y = (unsigned)f2bf(nw2) | ((unsigned)f2bf(nw3) << 16);
                *(uint2*)(sWT + col * SWT_STRIDE + nbase) = u;
                cs += nw0 + nw1 + nw2 + nw3;
            }
            cs += __shfl_xor(cs, 16);
            cs += __shfl_xor(cs, 32);
            if (quad == 0) atomicAdd(&sVs[it * HID + col], cs);
        }
    }
    __syncthreads();

    // ---- projection: out[g][c] = vs . W[c] + b[c]  (waves 0..5, 2 outputs each)
    if (tid < 32 * OUTC) {
        int c = tid >> 5;
        int i = tid & 31;
        float p = 0.0f;
        const float* wr = W + c * (6 * HID);
        for (int h = i; h < 6 * HID; h += 32) p += sVs[h] * wr[h];
#pragma unroll
        for (int s = 16; s >= 1; s >>= 1) p += __shfl_down(p, s, 32);
        if (i == 0) out[g * OUTC + c] = p + bvec[c];
    }
}

extern "C" void kernel_launch(void* const* d_in, const int* in_sizes, int n_in,
                              void* d_out, int out_size, void* d_ws, size_t ws_size,
                              hipStream_t stream) {
    const float* x = (const float*)d_in[0];
    const float* W = (const float*)d_in[1];
    const float* b = (const float*)d_in[2];
    const int* ei = (const int*)d_in[4];
    float* out = (float*)d_out;
    unsigned int* bits = (unsigned int*)d_ws;  // 2048*128*16 B = 4 MB

    // allow >64KB dynamic LDS (110592 B); cheap + idempotent, safe every call
    hipFuncSetAttribute((const void*)walk_kernel,
                        hipFuncAttributeMaxDynamicSharedMemorySize, LDS_BYTES);

    hipMemsetAsync(bits, 0, (size_t)NGRAPH * MNODES * 4 * sizeof(unsigned int), stream);
    build_adj<<<NEDGE / 512, 512, 0, stream>>>(ei, bits);
    walk_kernel<<<NGRAPH, 512, LDS_BYTES, stream>>>(x, W, b, bits, out);
}

// Round 2
// 507.273 us; speedup vs baseline: 1.4855x; 1.4855x over previous
//
#include <hip/hip_runtime.h>
#include <stdint.h>

#define NGRAPH 2048
#define MNODES 128
#define HID 256
#define OUTC 12
#define NEDGE 2097152

typedef __attribute__((ext_vector_type(8))) short short8;
typedef __attribute__((ext_vector_type(4))) float v4f;

#define SLICE 64        // hidden columns per block
#define SWT_STRIDE 136  // node-dim stride (136 elem = 272 B, 16B-aligned, bank-friendly)

__device__ __forceinline__ unsigned short f2bf(float f) {
    unsigned int u = __builtin_bit_cast(unsigned int, f);
    u += 0x7fffu + ((u >> 16) & 1u);   // round-to-nearest-even
    return (unsigned short)(u >> 16);
}

// ---- build path A (fast): plain byte stores, no atomics.
// Assignment semantics: every writer writes 1, so races are benign & exact.
__global__ void build_bytes(const int* __restrict__ ei, unsigned char* __restrict__ Ab) {
    int e = blockIdx.x * blockDim.x + threadIdx.x;
    if (e >= NEDGE) return;
    int sN = ei[e];
    int dN = ei[NEDGE + e];
    int g = sN >> 7;
    int li = sN & 127;
    int lj = dN & 127;
    unsigned char* base = Ab + (size_t)g * (MNODES * MNODES);
    base[li * 128 + lj] = 1;
    base[lj * 128 + li] = 1;
}

// ---- build path B (fallback if ws too small): bitmask + atomicOr
__global__ void build_bits(const int* __restrict__ ei, unsigned int* __restrict__ bits) {
    int e = blockIdx.x * blockDim.x + threadIdx.x;
    if (e >= NEDGE) return;
    int sN = ei[e];
    int dN = ei[NEDGE + e];
    int g = sN >> 7;
    int li = sN & 127;
    int lj = dN & 127;
    unsigned int* base = bits + (size_t)g * (MNODES * 4);
    atomicOr(&base[li * 4 + (lj >> 5)], 1u << (lj & 31));
    atomicOr(&base[lj * 4 + (li >> 5)], 1u << (li & 31));
}

// ---- walk kernel: block = (graph, 64-col hidden slice). 4 waves; wave w owns
// rows (w>>1)*64..+63, cols (w&1)*32..+31 of the slice. A fragments live in
// registers for all 5 iterations; walk^T round-trips through 17KB of LDS.
__launch_bounds__(256, 3)
__global__ void walk2(const float* __restrict__ x,
                      const float* __restrict__ W,
                      const unsigned char* __restrict__ Abytes,
                      const unsigned int* __restrict__ Abits,
                      int use_bytes,
                      float* __restrict__ partial) {
    __shared__ unsigned short sWT[SLICE][SWT_STRIDE];  // walk^T: [col][node]
    __shared__ float sVs2[2][6][SLICE];                // per-row-half col sums

    const int bx = blockIdx.x;
    const int g = bx >> 2;
    const int s = bx & 3;
    const int tid = threadIdx.x;
    const int wave = tid >> 6;
    const int lane = tid & 63;
    const int lrow = lane & 15;
    const int quad = lane >> 4;
    const int rhalf = wave >> 1;
    const int r0 = rhalf * 64;
    const int c0 = (wave & 1) * 32;      // col base within slice
    const int cg0 = s * SLICE + c0;      // global col base

    // ---- A fragments -> registers (fixed across iterations)
    short8 areg[4][4];  // [rt][ks]
    if (use_bytes) {
        const unsigned char* Ag = Abytes + (size_t)g * (MNODES * MNODES);
#pragma unroll
        for (int rt = 0; rt < 4; rt++) {
            int row = r0 + rt * 16 + lrow;
#pragma unroll
            for (int ks = 0; ks < 4; ks++) {
                int k0 = ks * 32 + quad * 8;
                uint2 u = *(const uint2*)(Ag + row * 128 + k0);
                short8 a;
#pragma unroll
                for (int j = 0; j < 8; j++) {
                    unsigned int byte = ((j < 4 ? u.x >> (8 * j) : u.y >> (8 * (j - 4))) & 0xFFu);
                    a[j] = (short)(byte ? 0x3F80 : 0);
                }
                areg[rt][ks] = a;
            }
        }
    } else {
        const unsigned int* Bg = Abits + (size_t)g * (MNODES * 4);
#pragma unroll
        for (int rt = 0; rt < 4; rt++) {
            int row = r0 + rt * 16 + lrow;
#pragma unroll
            for (int ks = 0; ks < 4; ks++) {
                unsigned int w = Bg[row * 4 + ks] >> (quad * 8);
                short8 a;
#pragma unroll
                for (int j = 0; j < 8; j++)
                    a[j] = (short)(((w >> j) & 1u) ? 0x3F80 : 0);
                areg[rt][ks] = a;
            }
        }
    }

    // ---- X fragments (fp32, C-layout), init walk1 = X, v1 partial sums
    float xf[4][2][4];
    const float* xg = x + (size_t)g * (MNODES * HID);
#pragma unroll
    for (int rt = 0; rt < 4; rt++)
#pragma unroll
        for (int ct = 0; ct < 2; ct++) {
            int col = cg0 + ct * 16 + lrow;
#pragma unroll
            for (int reg = 0; reg < 4; reg++) {
                int row = r0 + rt * 16 + quad * 4 + reg;
                xf[rt][ct][reg] = xg[row * HID + col];
            }
        }
#pragma unroll
    for (int ct = 0; ct < 2; ct++) {
        int lcol = c0 + ct * 16 + lrow;
        float cs = 0.0f;
#pragma unroll
        for (int rt = 0; rt < 4; rt++) {
            int nbase = r0 + rt * 16 + quad * 4;
            uint2 u;
            u.x = (unsigned)f2bf(xf[rt][ct][0]) | ((unsigned)f2bf(xf[rt][ct][1]) << 16);
            u.y = (unsigned)f2bf(xf[rt][ct][2]) | ((unsigned)f2bf(xf[rt][ct][3]) << 16);
            *(uint2*)&sWT[lcol][nbase] = u;
            cs += xf[rt][ct][0] + xf[rt][ct][1] + xf[rt][ct][2] + xf[rt][ct][3];
        }
        cs += __shfl_xor(cs, 16);
        cs += __shfl_xor(cs, 32);
        if (quad == 0) sVs2[rhalf][0][lcol] = cs;   // waves of same rhalf own disjoint lcol
    }
    __syncthreads();

    // ---- 5 iterations: Y = A@walk (MFMA, A from regs), walk = Y.*X, col sums
    for (int it = 1; it <= 5; it++) {
        v4f acc[4][2];
#pragma unroll
        for (int rt = 0; rt < 4; rt++)
#pragma unroll
            for (int ct = 0; ct < 2; ct++) acc[rt][ct] = (v4f)(0.0f);
#pragma unroll
        for (int ks = 0; ks < 4; ks++) {
            int k0 = ks * 32 + quad * 8;
#pragma unroll
            for (int ct = 0; ct < 2; ct++) {
                short8 bf = *(const short8*)&sWT[c0 + ct * 16 + lrow][k0];
#pragma unroll
                for (int rt = 0; rt < 4; rt++)
                    acc[rt][ct] = __builtin_amdgcn_mfma_f32_16x16x32_bf16(areg[rt][ks], bf, acc[rt][ct], 0, 0, 0);
            }
        }
        __syncthreads();  // all reads done before overwrite
#pragma unroll
        for (int ct = 0; ct < 2; ct++) {
            int lcol = c0 + ct * 16 + lrow;
            float cs = 0.0f;
#pragma unroll
            for (int rt = 0; rt < 4; rt++) {
                float nw0 = acc[rt][ct][0] * xf[rt][ct][0];
                float nw1 = acc[rt][ct][1] * xf[rt][ct][1];
                float nw2 = acc[rt][ct][2] * xf[rt][ct][2];
                float nw3 = acc[rt][ct][3] * xf[rt][ct][3];
                int nbase = r0 + rt * 16 + quad * 4;
                uint2 u;
                u.x = (unsigned)f2bf(nw0) | ((unsigned)f2bf(nw1) << 16);
                u.y = (unsigned)f2bf(nw2) | ((unsigned)f2bf(nw3) << 16);
                *(uint2*)&sWT[lcol][nbase] = u;
                cs += nw0 + nw1 + nw2 + nw3;
            }
            cs += __shfl_xor(cs, 16);
            cs += __shfl_xor(cs, 32);
            if (quad == 0) sVs2[rhalf][it][lcol] = cs;
        }
        __syncthreads();  // walk ready for next iteration (also publishes sVs2)
    }

    // ---- per-block partial projection over this 6x64 slice of vs
    if (wave == 0) {
        for (int c = 0; c < OUTC; c++) {
            float p = 0.0f;
            const float* wr = W + c * (6 * HID);
#pragma unroll
            for (int ii = 0; ii < 6; ii++) {
                int i = ii * 64 + lane;
                int k = i >> 6;
                int h = i & 63;
                float v = sVs2[0][k][h] + sVs2[1][k][h];
                p += v * wr[k * HID + s * SLICE + h];
            }
#pragma unroll
            for (int off = 32; off >= 1; off >>= 1) p += __shfl_down(p, off);
            if (lane == 0) partial[bx * OUTC + c] = p;
        }
    }
}

// ---- combine the 4 slice partials + bias
__global__ void combine(const float* __restrict__ partial, const float* __restrict__ bvec,
                        float* __restrict__ out) {
    int i = blockIdx.x * blockDim.x + threadIdx.x;
    if (i >= NGRAPH * OUTC) return;
    int c = i % OUTC;
    int g = i / OUTC;
    float p = bvec[c];
#pragma unroll
    for (int s = 0; s < 4; s++) p += partial[(g * 4 + s) * OUTC + c];
    out[i] = p;
}

extern "C" void kernel_launch(void* const* d_in, const int* in_sizes, int n_in,
                              void* d_out, int out_size, void* d_ws, size_t ws_size,
                              hipStream_t stream) {
    const float* x = (const float*)d_in[0];
    const float* W = (const float*)d_in[1];
    const float* b = (const float*)d_in[2];
    const int* ei = (const int*)d_in[4];
    float* out = (float*)d_out;

    const size_t ABYTES = (size_t)NGRAPH * MNODES * MNODES;        // 32 MB
    const size_t PARTIAL = (size_t)NGRAPH * 4 * OUTC * sizeof(float);

    if (ws_size >= ABYTES + PARTIAL) {
        unsigned char* Ab = (unsigned char*)d_ws;
        float* partial = (float*)((char*)d_ws + ABYTES);
        hipMemsetAsync(Ab, 0, ABYTES, stream);
        build_bytes<<<NEDGE / 256, 256, 0, stream>>>(ei, Ab);
        walk2<<<NGRAPH * 4, 256, 0, stream>>>(x, W, Ab, nullptr, 1, partial);
        combine<<<(NGRAPH * OUTC + 255) / 256, 256, 0, stream>>>(partial, b, out);
    } else {
        unsigned int* bits = (unsigned int*)d_ws;   // 4 MB
        float* partial = (float*)((char*)d_ws + (size_t)NGRAPH * MNODES * 4 * 4);
        hipMemsetAsync(bits, 0, (size_t)NGRAPH * MNODES * 4 * 4, stream);
        build_bits<<<NEDGE / 512, 512, 0, stream>>>(ei, bits);
        walk2<<<NGRAPH * 4, 256, 0, stream>>>(x, W, nullptr, bits, 0, partial);
        combine<<<(NGRAPH * OUTC + 255) / 256, 256, 0, stream>>>(partial, b, out);
    }
}